// Round 6
// baseline (545.734 us; speedup 1.0000x reference)
//
#include <hip/hip_runtime.h>
#include <hip/hip_bf16.h>

// N=50000, F=256, E=800000, H=4, P=65
#define K_DIM 256
#define RQ    512          // qkb row stride in bf16 elems (1024 B): [q 4x64 | k 4x64]
#define NPAD  640          // GEMM col padding: 5 tiles of 128
#define GBM 128
#define GBN 128
#define GBK 32
#define EPITCH 152         // epilogue LDS pitch (elems)
#define NBP   800          // bucket array allocation (NB = ceil(M/64) = 782)

typedef unsigned short u16;
using short8  = __attribute__((ext_vector_type(8))) short;
using ushort8 = __attribute__((ext_vector_type(8))) unsigned short;
using f32x4   = __attribute__((ext_vector_type(4))) float;
using f32x2   = __attribute__((ext_vector_type(2))) float;

__device__ __forceinline__ float asf(unsigned u) {
  union { unsigned i; float f; } x; x.i = u; return x.f;
}
__device__ __forceinline__ u16 f2b(float f) {
  __hip_bfloat16 h = __float2bfloat16(f); return *(u16*)&h;
}

// stored column p -> original W row c, or -1 for pad
__device__ __forceinline__ int map2(int p) {
  if (p < 256) return (p >> 6) * 130 + (p & 63);
  if (p < 512) { int q = p - 256; return (q >> 6) * 130 + 65 + (q & 63); }
  if (p < 516) return (p - 512) * 130 + 64;
  if (p < 520) return (p - 516) * 130 + 129;
  return -1;
}

// Fused: convert_x | convert_w(+bias) | zero (denom + cnt + cursor)
__global__ void __launch_bounds__(256) prep(
    const float* __restrict__ x, const float* __restrict__ W,
    const float* __restrict__ bv,
    u16* __restrict__ xb, u16* __restrict__ wb,
    float* __restrict__ bias, float* __restrict__ zbase,
    int M, int Mpad, int xblocks, int wblocks, int zn)
{
  const int blk = blockIdx.x, tid = threadIdx.x;
  if (blk < xblocks) {
    int idx = blk * 256 + tid;
    int total = Mpad * (K_DIM / 8);
    if (idx >= total) return;
    int row = idx / (K_DIM / 8);
    ushort8 o;
    if (row < M) {
      const float* s = x + (size_t)idx * 8;
      float4 a = *(const float4*)s;
      float4 b = *(const float4*)(s + 4);
      o[0] = f2b(a.x); o[1] = f2b(a.y); o[2] = f2b(a.z); o[3] = f2b(a.w);
      o[4] = f2b(b.x); o[5] = f2b(b.y); o[6] = f2b(b.z); o[7] = f2b(b.w);
    } else {
      #pragma unroll
      for (int j = 0; j < 8; ++j) o[j] = 0;
    }
    *(ushort8*)(xb + (size_t)idx * 8) = o;
  } else if (blk < xblocks + wblocks) {
    int idx = (blk - xblocks) * 256 + tid;
    int total = NPAD * (K_DIM / 8);
    if (idx >= total) return;
    int p  = idx / (K_DIM / 8);
    int kc = (idx % (K_DIM / 8)) * 8;
    int c  = map2(p);
    ushort8 o;
    if (c >= 0) {
      const float* s = W + (size_t)c * K_DIM + kc;
      float4 a = *(const float4*)s;
      float4 v = *(const float4*)(s + 4);
      o[0] = f2b(a.x); o[1] = f2b(a.y); o[2] = f2b(a.z); o[3] = f2b(a.w);
      o[4] = f2b(v.x); o[5] = f2b(v.y); o[6] = f2b(v.z); o[7] = f2b(v.w);
    } else {
      #pragma unroll
      for (int j = 0; j < 8; ++j) o[j] = 0;
    }
    *(ushort8*)(wb + (size_t)idx * 8) = o;
    if (kc == 0) bias[p] = (c >= 0) ? bv[c] : 0.f;
  } else {
    int i = (blk - xblocks - wblocks) * 256 + tid;
    if (i < zn) zbase[i] = 0.f;
  }
}

// qk = xb @ wb^T + bias (bf16 MFMA), double-buffered stage, LDS-staged epilogue.
__global__ void __launch_bounds__(256) gemm_mfma(
    const u16* __restrict__ xb, const u16* __restrict__ wb,
    const float* __restrict__ bias, u16* __restrict__ qkb,
    u16* __restrict__ tl, int M)
{
  __shared__ u16 smem[GBM * EPITCH];
  const int tid  = threadIdx.x;
  const int wave = tid >> 6, lane = tid & 63;
  const int l15 = lane & 15, lhi = lane >> 4;
  const int row0 = blockIdx.x * GBM, p0 = blockIdx.y * GBN;
  const int wr = (wave >> 1) * 64, wc = (wave & 1) * 64;

  f32x4 acc[4][4];
  #pragma unroll
  for (int m = 0; m < 4; ++m)
    #pragma unroll
    for (int n = 0; n < 4; ++n) acc[m][n] = (f32x4){0.f, 0.f, 0.f, 0.f};

#define STAGE(b, k0) do {                                                     \
    u16* As_ = smem + (b) * 8192;                                             \
    u16* Bs_ = As_ + 4096;                                                    \
    _Pragma("unroll")                                                         \
    for (int i_ = 0; i_ < 2; ++i_) {                                          \
      int f_ = wave * 128 + i_ * 64 + lane;                                   \
      int r_ = f_ >> 2, c_ = f_ & 3;                                          \
      const u16* gA = xb + (size_t)(row0 + r_) * K_DIM + (k0) + c_ * 8;       \
      __builtin_amdgcn_global_load_lds(                                       \
          (const __attribute__((address_space(1))) void*)gA,                  \
          (__attribute__((address_space(3))) void*)(As_ + (wave*128 + i_*64)*8), \
          16, 0, 0);                                                          \
      const u16* gB = wb + (size_t)(p0 + r_) * K_DIM + (k0) + c_ * 8;         \
      __builtin_amdgcn_global_load_lds(                                       \
          (const __attribute__((address_space(1))) void*)gB,                  \
          (__attribute__((address_space(3))) void*)(Bs_ + (wave*128 + i_*64)*8), \
          16, 0, 0);                                                          \
    }                                                                         \
  } while (0)

  STAGE(0, 0);
  asm volatile("s_waitcnt vmcnt(0)" ::: "memory");
  __syncthreads();

  #pragma unroll
  for (int t = 0; t < K_DIM / GBK; ++t) {
    if (t < K_DIM / GBK - 1) STAGE((t + 1) & 1, (t + 1) * GBK);
    const u16* As = smem + (t & 1) * 8192;
    const u16* Bs = As + 4096;
    short8 af[4], bf[4];
    #pragma unroll
    for (int m = 0; m < 4; ++m)
      af[m] = *(const short8*)(As + (size_t)(wr + m * 16 + l15) * GBK + lhi * 8);
    #pragma unroll
    for (int n = 0; n < 4; ++n)
      bf[n] = *(const short8*)(Bs + (size_t)(wc + n * 16 + l15) * GBK + lhi * 8);
    #pragma unroll
    for (int m = 0; m < 4; ++m)
      #pragma unroll
      for (int n = 0; n < 4; ++n)
        acc[m][n] = __builtin_amdgcn_mfma_f32_16x16x32_bf16(af[m], bf[n], acc[m][n], 0, 0, 0);
    if (t < K_DIM / GBK - 1) {
      asm volatile("s_waitcnt vmcnt(0)" ::: "memory");
      __syncthreads();
    }
  }
#undef STAGE

  __syncthreads();

  #pragma unroll
  for (int n = 0; n < 4; ++n) {
    int col = wc + n * 16 + l15;
    float bvv = bias[p0 + col];
    #pragma unroll
    for (int m = 0; m < 4; ++m) {
      #pragma unroll
      for (int r = 0; r < 4; ++r) {
        int row = wr + m * 16 + lhi * 4 + r;
        smem[row * EPITCH + col] = f2b(acc[m][n][r] + bvv);
      }
    }
  }
  __syncthreads();

  if (p0 < 512) {
    #pragma unroll
    for (int it = 0; it < 8; ++it) {
      int row  = wave * 32 + it * 4 + lhi;
      int grow = row0 + row;
      uint4 v = *(const uint4*)(smem + row * EPITCH + l15 * 8);
      if (grow < M)
        *(uint4*)(qkb + (size_t)grow * RQ + p0 + l15 * 8) = v;
    }
  } else {
    #pragma unroll
    for (int it = 0; it < 8; ++it) {
      int row  = wave * 32 + it * 4 + lhi;
      int grow = row0 + row;
      if (l15 == 0 && grow < M) {
        uint4 v = *(const uint4*)(smem + row * EPITCH);
        *(uint4*)(tl + (size_t)grow * 8) = v;
      }
    }
  }
}

// --- bucket sort by src>>6 ---
__global__ void __launch_bounds__(256) hist_k(
    const int* __restrict__ ei, int* __restrict__ cnt, int E)
{
  int i = blockIdx.x * 256 + threadIdx.x;
  if (i < E) atomicAdd(&cnt[ei[i] >> 6], 1);
}

__global__ void __launch_bounds__(1024) scan_k(
    const int* __restrict__ cnt, int* __restrict__ cursor, int NB)
{
  __shared__ int s[1024];
  int t = threadIdx.x;
  int own = (t < NB) ? cnt[t] : 0;
  s[t] = own;
  __syncthreads();
  #pragma unroll
  for (int off = 1; off < 1024; off <<= 1) {
    int u = (t >= off) ? s[t - off] : 0;
    __syncthreads();
    s[t] += u;
    __syncthreads();
  }
  if (t < NB) cursor[t] = s[t] - own;   // exclusive prefix
}

__global__ void __launch_bounds__(256) scatter_k(
    const int* __restrict__ ei, int* __restrict__ cursor,
    uint4* __restrict__ sorted, int E)
{
  int i = blockIdx.x * 256 + threadIdx.x;
  if (i >= E) return;
  int src = ei[i], dst = ei[E + i];
  int pos = atomicAdd(&cursor[src >> 6], 1);
  sorted[pos] = make_uint4((unsigned)src, (unsigned)dst, (unsigned)i, 0u);
}

// 8 edges per wave, 8 lanes per edge; walks src-bucketed sorted slots with
// bijective XCD-aware block swizzle so each XCD sees a contiguous slot range.
__global__ void __launch_bounds__(256) edge_pass(
    const u16* __restrict__ qkb, const u16* __restrict__ tl,
    const uint4* __restrict__ sorted,
    float* __restrict__ exb, float* __restrict__ denom, int E)
{
  const int tid  = threadIdx.x;
  const int wave = tid >> 6, lane = tid & 63;
  const int g = lane >> 3;
  const int l = lane & 7;

  // bijective XCD swizzle (m204): block bid -> chunk swz
  const int nwg = gridDim.x;
  const int q8 = nwg >> 3, r8 = nwg & 7;
  const int xcd = blockIdx.x & 7, bix = blockIdx.x >> 3;
  const int swz = (xcd < r8) ? (xcd * (q8 + 1) + bix)
                             : (r8 * (q8 + 1) + (xcd - r8) * q8 + bix);

  const int slot = swz * 32 + wave * 8 + g;
  const bool valid = slot < E;
  uint4 tr = sorted[valid ? slot : 0];
  const int src = tr.x, dst = tr.y, e = tr.z;

  const u16* qrow = qkb + ((size_t)src * RQ) + l * 32;
  const u16* krow = qkb + ((size_t)dst * RQ) + 256 + l * 32;

  int2 ti = make_int2(0, 0);
  if (l < 2) {
    const u16* tp = tl + (size_t)(l ? dst : src) * 8 + (l ? 4 : 0);
    ti = *(const int2*)tp;
  }

  f32x2 a2 = {0.f, 0.f};
  #pragma unroll
  for (int c = 0; c < 4; ++c) {
    uint4 qv = *(const uint4*)(qrow + c * 8);
    uint4 kv = *(const uint4*)(krow + c * 8);
    const unsigned* qd = (const unsigned*)&qv;
    const unsigned* kd = (const unsigned*)&kv;
    #pragma unroll
    for (int j = 0; j < 4; ++j) {
      f32x2 qa = { asf(qd[j] << 16), asf(qd[j] & 0xffff0000u) };
      f32x2 ka = { asf(kd[j] << 16), asf(kd[j] & 0xffff0000u) };
      a2 += qa * ka;
    }
  }
  float s = a2[0] + a2[1];
  s += __shfl_xor(s, 1);            // head sum (lanes 2h, 2h+1)

  const int h = l >> 1;
  int idxA = ((g << 3) | (l & 1)) << 2;
  int w01 = __builtin_amdgcn_ds_bpermute(idxA, ti.x);
  int w23 = __builtin_amdgcn_ds_bpermute(idxA, ti.y);
  unsigned wsel = (h & 2) ? (unsigned)w23 : (unsigned)w01;
  float tv = (h & 1) ? asf(wsel & 0xffff0000u) : asf(wsel << 16);
  float to = __shfl_xor(tv, 1);
  s = fmaf(tv, to, s);

  float ev = __expf(s);             // |s| <~ 8: fp32-safe, no max-subtraction
  if (valid && (l & 1) == 0) {
    exb[(size_t)e * 4 + h] = ev;
    unsafeAtomicAdd(&denom[(size_t)src * 4 + h], ev);
  }
}

__global__ void __launch_bounds__(256) finalize_k(
    const float* __restrict__ exb, const float* __restrict__ denom,
    const int* __restrict__ ei, float* __restrict__ out, int E)
{
  int e = blockIdx.x * 256 + threadIdx.x;
  if (e >= E) return;
  int src = ei[e];
  float4 ev = *(const float4*)(exb + (size_t)e * 4);
  float4 dv = *(const float4*)(denom + (size_t)src * 4);
  out[e] = 0.25f * (ev.x / dv.x + ev.y / dv.y + ev.z / dv.z + ev.w / dv.w);
}

extern "C" void kernel_launch(void* const* d_in, const int* in_sizes, int n_in,
                              void* d_out, int out_size, void* d_ws, size_t ws_size,
                              hipStream_t stream)
{
  const float* x  = (const float*)d_in[0];
  const int*   ei = (const int*)d_in[1];
  const float* W  = (const float*)d_in[2];
  const float* b  = (const float*)d_in[3];

  const int F = in_sizes[2] / in_sizes[3];   // 256
  const int M = in_sizes[0] / F;             // 50000
  const int E = in_sizes[1] / 2;             // 800000
  const int NB = (M + 63) >> 6;              // 782 buckets

  const int mblocks = (M + GBM - 1) / GBM;
  const int Mpad    = mblocks * GBM;

  // ws: xb | wb | qkb | tl | bias | exb | denom | cnt[NBP] | cursor[NBP] | sorted
  u16* xb  = (u16*)d_ws;
  u16* wb  = xb + (size_t)Mpad * K_DIM;
  u16* qkb = wb + (size_t)NPAD * K_DIM;
  u16* tl  = qkb + (size_t)M * RQ;
  float* bias  = (float*)(tl + (size_t)M * 8);
  float* exb   = bias + NPAD;
  float* denom = exb + (size_t)E * 4;
  int*   cnt    = (int*)(denom + (size_t)M * 4);
  int*   cursor = cnt + NBP;
  uint4* sorted = (uint4*)(cursor + NBP);

  const int xblocks = (Mpad * (K_DIM / 8) + 255) / 256;
  const int wblocks = (NPAD * (K_DIM / 8) + 255) / 256;
  const int zn      = M * 4 + 2 * NBP;       // denom + cnt + cursor (contiguous)
  const int zblocks = (zn + 255) / 256;
  hipLaunchKernelGGL(prep, dim3(xblocks + wblocks + zblocks), dim3(256), 0, stream,
                     x, W, b, xb, wb, bias, denom, M, Mpad, xblocks, wblocks, zn);

  const int eb256 = (E + 255) / 256;
  hipLaunchKernelGGL(hist_k, dim3(eb256), dim3(256), 0, stream, ei, cnt, E);
  hipLaunchKernelGGL(scan_k, dim3(1), dim3(1024), 0, stream, cnt, cursor, NB);

  dim3 gg(mblocks, NPAD / GBN);
  hipLaunchKernelGGL(gemm_mfma, gg, dim3(256), 0, stream, xb, wb, bias, qkb, tl, M);

  hipLaunchKernelGGL(scatter_k, dim3(eb256), dim3(256), 0, stream, ei, cursor, sorted, E);

  int eblocks = (E + 31) / 32;   // 32 sorted slots per block
  hipLaunchKernelGGL(edge_pass, dim3(eblocks), dim3(256), 0, stream,
                     qkb, tl, sorted, exb, denom, E);

  hipLaunchKernelGGL(finalize_k, dim3((E + 255) / 256), dim3(256), 0, stream,
                     exb, denom, ei, (float*)d_out, E);
}

// Round 7
// 173.363 us; speedup vs baseline: 3.1479x; 3.1479x over previous
//
#include <hip/hip_runtime.h>
#include <hip/hip_bf16.h>

// N=50000, F=256, E=800000, H=4, P=65
#define K_DIM 256
#define RQ    512          // qkb row stride in bf16 elems (1024 B): [q 4x64 | k 4x64]
#define NPAD  640          // GEMM col padding: 5 tiles of 128
#define GBM 128
#define GBN 128
#define GBK 32
#define EPITCH 152         // epilogue LDS pitch (elems)
#define NBK   64           // bucket slots (used: ceil(50000/1024)=49)
#define CBLK  256          // count/scatter blocks

typedef unsigned short u16;
using short8  = __attribute__((ext_vector_type(8))) short;
using ushort8 = __attribute__((ext_vector_type(8))) unsigned short;
using f32x4   = __attribute__((ext_vector_type(4))) float;
using f32x2   = __attribute__((ext_vector_type(2))) float;

__device__ __forceinline__ float asf(unsigned u) {
  union { unsigned i; float f; } x; x.i = u; return x.f;
}
__device__ __forceinline__ u16 f2b(float f) {
  __hip_bfloat16 h = __float2bfloat16(f); return *(u16*)&h;
}

// stored column p -> original W row c, or -1 for pad
__device__ __forceinline__ int map2(int p) {
  if (p < 256) return (p >> 6) * 130 + (p & 63);
  if (p < 512) { int q = p - 256; return (q >> 6) * 130 + 65 + (q & 63); }
  if (p < 516) return (p - 512) * 130 + 64;
  if (p < 520) return (p - 516) * 130 + 129;
  return -1;
}

// Fused: convert_x | convert_w(+bias) | zero denom
__global__ void __launch_bounds__(256) prep(
    const float* __restrict__ x, const float* __restrict__ W,
    const float* __restrict__ bv,
    u16* __restrict__ xb, u16* __restrict__ wb,
    float* __restrict__ bias, float* __restrict__ zbase,
    int M, int Mpad, int xblocks, int wblocks, int zn)
{
  const int blk = blockIdx.x, tid = threadIdx.x;
  if (blk < xblocks) {
    int idx = blk * 256 + tid;
    int total = Mpad * (K_DIM / 8);
    if (idx >= total) return;
    int row = idx / (K_DIM / 8);
    ushort8 o;
    if (row < M) {
      const float* s = x + (size_t)idx * 8;
      float4 a = *(const float4*)s;
      float4 b = *(const float4*)(s + 4);
      o[0] = f2b(a.x); o[1] = f2b(a.y); o[2] = f2b(a.z); o[3] = f2b(a.w);
      o[4] = f2b(b.x); o[5] = f2b(b.y); o[6] = f2b(b.z); o[7] = f2b(b.w);
    } else {
      #pragma unroll
      for (int j = 0; j < 8; ++j) o[j] = 0;
    }
    *(ushort8*)(xb + (size_t)idx * 8) = o;
  } else if (blk < xblocks + wblocks) {
    int idx = (blk - xblocks) * 256 + tid;
    int total = NPAD * (K_DIM / 8);
    if (idx >= total) return;
    int p  = idx / (K_DIM / 8);
    int kc = (idx % (K_DIM / 8)) * 8;
    int c  = map2(p);
    ushort8 o;
    if (c >= 0) {
      const float* s = W + (size_t)c * K_DIM + kc;
      float4 a = *(const float4*)s;
      float4 v = *(const float4*)(s + 4);
      o[0] = f2b(a.x); o[1] = f2b(a.y); o[2] = f2b(a.z); o[3] = f2b(a.w);
      o[4] = f2b(v.x); o[5] = f2b(v.y); o[6] = f2b(v.z); o[7] = f2b(v.w);
    } else {
      #pragma unroll
      for (int j = 0; j < 8; ++j) o[j] = 0;
    }
    *(ushort8*)(wb + (size_t)idx * 8) = o;
    if (kc == 0) bias[p] = (c >= 0) ? bv[c] : 0.f;
  } else {
    int i = (blk - xblocks - wblocks) * 256 + tid;
    if (i < zn) zbase[i] = 0.f;
  }
}

// qk = xb @ wb^T + bias (bf16 MFMA), double-buffered stage, LDS-staged epilogue.
__global__ void __launch_bounds__(256) gemm_mfma(
    const u16* __restrict__ xb, const u16* __restrict__ wb,
    const float* __restrict__ bias, u16* __restrict__ qkb,
    u16* __restrict__ tl, int M)
{
  __shared__ u16 smem[GBM * EPITCH];
  const int tid  = threadIdx.x;
  const int wave = tid >> 6, lane = tid & 63;
  const int l15 = lane & 15, lhi = lane >> 4;
  const int row0 = blockIdx.x * GBM, p0 = blockIdx.y * GBN;
  const int wr = (wave >> 1) * 64, wc = (wave & 1) * 64;

  f32x4 acc[4][4];
  #pragma unroll
  for (int m = 0; m < 4; ++m)
    #pragma unroll
    for (int n = 0; n < 4; ++n) acc[m][n] = (f32x4){0.f, 0.f, 0.f, 0.f};

#define STAGE(b, k0) do {                                                     \
    u16* As_ = smem + (b) * 8192;                                             \
    u16* Bs_ = As_ + 4096;                                                    \
    _Pragma("unroll")                                                         \
    for (int i_ = 0; i_ < 2; ++i_) {                                          \
      int f_ = wave * 128 + i_ * 64 + lane;                                   \
      int r_ = f_ >> 2, c_ = f_ & 3;                                          \
      const u16* gA = xb + (size_t)(row0 + r_) * K_DIM + (k0) + c_ * 8;       \
      __builtin_amdgcn_global_load_lds(                                       \
          (const __attribute__((address_space(1))) void*)gA,                  \
          (__attribute__((address_space(3))) void*)(As_ + (wave*128 + i_*64)*8), \
          16, 0, 0);                                                          \
      const u16* gB = wb + (size_t)(p0 + r_) * K_DIM + (k0) + c_ * 8;         \
      __builtin_amdgcn_global_load_lds(                                       \
          (const __attribute__((address_space(1))) void*)gB,                  \
          (__attribute__((address_space(3))) void*)(Bs_ + (wave*128 + i_*64)*8), \
          16, 0, 0);                                                          \
    }                                                                         \
  } while (0)

  STAGE(0, 0);
  asm volatile("s_waitcnt vmcnt(0)" ::: "memory");
  __syncthreads();

  #pragma unroll
  for (int t = 0; t < K_DIM / GBK; ++t) {
    if (t < K_DIM / GBK - 1) STAGE((t + 1) & 1, (t + 1) * GBK);
    const u16* As = smem + (t & 1) * 8192;
    const u16* Bs = As + 4096;
    short8 af[4], bf[4];
    #pragma unroll
    for (int m = 0; m < 4; ++m)
      af[m] = *(const short8*)(As + (size_t)(wr + m * 16 + l15) * GBK + lhi * 8);
    #pragma unroll
    for (int n = 0; n < 4; ++n)
      bf[n] = *(const short8*)(Bs + (size_t)(wc + n * 16 + l15) * GBK + lhi * 8);
    #pragma unroll
    for (int m = 0; m < 4; ++m)
      #pragma unroll
      for (int n = 0; n < 4; ++n)
        acc[m][n] = __builtin_amdgcn_mfma_f32_16x16x32_bf16(af[m], bf[n], acc[m][n], 0, 0, 0);
    if (t < K_DIM / GBK - 1) {
      asm volatile("s_waitcnt vmcnt(0)" ::: "memory");
      __syncthreads();
    }
  }
#undef STAGE

  __syncthreads();

  #pragma unroll
  for (int n = 0; n < 4; ++n) {
    int col = wc + n * 16 + l15;
    float bvv = bias[p0 + col];
    #pragma unroll
    for (int m = 0; m < 4; ++m) {
      #pragma unroll
      for (int r = 0; r < 4; ++r) {
        int row = wr + m * 16 + lhi * 4 + r;
        smem[row * EPITCH + col] = f2b(acc[m][n][r] + bvv);
      }
    }
  }
  __syncthreads();

  if (p0 < 512) {
    #pragma unroll
    for (int it = 0; it < 8; ++it) {
      int row  = wave * 32 + it * 4 + lhi;
      int grow = row0 + row;
      uint4 v = *(const uint4*)(smem + row * EPITCH + l15 * 8);
      if (grow < M)
        *(uint4*)(qkb + (size_t)grow * RQ + p0 + l15 * 8) = v;
    }
  } else {
    #pragma unroll
    for (int it = 0; it < 8; ++it) {
      int row  = wave * 32 + it * 4 + lhi;
      int grow = row0 + row;
      if (l15 == 0 && grow < M) {
        uint4 v = *(const uint4*)(smem + row * EPITCH);
        *(uint4*)(tl + (size_t)grow * 8) = v;
      }
    }
  }
}

// --- contention-free bucket sort by src>>10 (49 buckets, 64 slots) ---
// Pass 1: per-block LDS histogram -> counts[k][block]  (no global atomics)
__global__ void __launch_bounds__(256) count_k(
    const int* __restrict__ ei, int* __restrict__ counts, int E, int per)
{
  __shared__ int h[NBK];
  const int tid = threadIdx.x, blk = blockIdx.x;
  if (tid < NBK) h[tid] = 0;
  __syncthreads();
  int start = blk * per, end = min(start + per, E);
  for (int i = start + tid; i < end; i += 256)
    atomicAdd(&h[ei[i] >> 10], 1);
  __syncthreads();
  if (tid < NBK) counts[tid * CBLK + blk] = h[tid];
}

// Pass 2: in-place exclusive offsets: counts[k][b] -> base[k] + prefix_b
__global__ void __launch_bounds__(1024) scan_k(int* __restrict__ counts)
{
  __shared__ int tot[NBK], base[NBK];
  const int tid = threadIdx.x, wv = tid >> 6, ln = tid & 63;
  // totals per bucket
  for (int k = wv; k < NBK; k += 16) {
    int sum = 0;
    #pragma unroll
    for (int c = 0; c < CBLK / 64; ++c) sum += counts[k * CBLK + c * 64 + ln];
    #pragma unroll
    for (int off = 1; off < 64; off <<= 1) sum += __shfl_xor(sum, off);
    if (ln == 0) tot[k] = sum;
  }
  __syncthreads();
  if (wv == 0) {                      // exclusive scan of 64 totals
    int v = tot[ln], inc = v;
    #pragma unroll
    for (int off = 1; off < 64; off <<= 1) {
      int u = __shfl_up(inc, off);
      if (ln >= off) inc += u;
    }
    base[ln] = inc - v;
  }
  __syncthreads();
  for (int k = wv; k < NBK; k += 16) {
    int carry = base[k];
    #pragma unroll
    for (int c = 0; c < CBLK / 64; ++c) {
      int v = counts[k * CBLK + c * 64 + ln];
      int inc = v;
      #pragma unroll
      for (int off = 1; off < 64; off <<= 1) {
        int u = __shfl_up(inc, off);
        if (ln >= off) inc += u;
      }
      int last = __shfl(inc, 63);
      counts[k * CBLK + c * 64 + ln] = carry + inc - v;
      carry += last;
    }
  }
}

// Pass 3: scatter with LDS cursors (global-atomic-free)
__global__ void __launch_bounds__(256) scatter2_k(
    const int* __restrict__ ei, const int* __restrict__ offs,
    uint4* __restrict__ sorted, int E, int per)
{
  __shared__ int cur[NBK];
  const int tid = threadIdx.x, blk = blockIdx.x;
  if (tid < NBK) cur[tid] = offs[tid * CBLK + blk];
  __syncthreads();
  int start = blk * per, end = min(start + per, E);
  for (int i = start + tid; i < end; i += 256) {
    int s = ei[i], d = ei[E + i];
    int pos = atomicAdd(&cur[s >> 10], 1);
    sorted[pos] = make_uint4((unsigned)s, (unsigned)d, (unsigned)i, 0u);
  }
}

// 8 edges per wave, 8 lanes per edge; src-bucketed slots + bijective XCD chunking.
__global__ void __launch_bounds__(256) edge_pass(
    const u16* __restrict__ qkb, const u16* __restrict__ tl,
    const uint4* __restrict__ sorted,
    float* __restrict__ exb, float* __restrict__ denom, int E)
{
  const int tid  = threadIdx.x;
  const int wave = tid >> 6, lane = tid & 63;
  const int g = lane >> 3;
  const int l = lane & 7;

  const int nwg = gridDim.x;
  const int q8 = nwg >> 3, r8 = nwg & 7;
  const int xcd = blockIdx.x & 7, bix = blockIdx.x >> 3;
  const int swz = (xcd < r8) ? (xcd * (q8 + 1) + bix)
                             : (r8 * (q8 + 1) + (xcd - r8) * q8 + bix);

  const int slot = swz * 32 + wave * 8 + g;
  const bool valid = slot < E;
  uint4 tr = sorted[valid ? slot : 0];
  const int src = tr.x, dst = tr.y, e = tr.z;

  const u16* qrow = qkb + ((size_t)src * RQ) + l * 32;
  const u16* krow = qkb + ((size_t)dst * RQ) + 256 + l * 32;

  int2 ti = make_int2(0, 0);
  if (l < 2) {
    const u16* tp = tl + (size_t)(l ? dst : src) * 8 + (l ? 4 : 0);
    ti = *(const int2*)tp;
  }

  f32x2 a2 = {0.f, 0.f};
  #pragma unroll
  for (int c = 0; c < 4; ++c) {
    uint4 qv = *(const uint4*)(qrow + c * 8);
    uint4 kv = *(const uint4*)(krow + c * 8);
    const unsigned* qd = (const unsigned*)&qv;
    const unsigned* kd = (const unsigned*)&kv;
    #pragma unroll
    for (int j = 0; j < 4; ++j) {
      f32x2 qa = { asf(qd[j] << 16), asf(qd[j] & 0xffff0000u) };
      f32x2 ka = { asf(kd[j] << 16), asf(kd[j] & 0xffff0000u) };
      a2 += qa * ka;
    }
  }
  float s = a2[0] + a2[1];
  s += __shfl_xor(s, 1);            // head sum (lanes 2h, 2h+1)

  const int h = l >> 1;
  int idxA = ((g << 3) | (l & 1)) << 2;
  int w01 = __builtin_amdgcn_ds_bpermute(idxA, ti.x);
  int w23 = __builtin_amdgcn_ds_bpermute(idxA, ti.y);
  unsigned wsel = (h & 2) ? (unsigned)w23 : (unsigned)w01;
  float tv = (h & 1) ? asf(wsel & 0xffff0000u) : asf(wsel << 16);
  float to = __shfl_xor(tv, 1);
  s = fmaf(tv, to, s);

  float ev = __expf(s);             // |s| <~ 8: fp32-safe, no max-subtraction
  if (valid && (l & 1) == 0) {
    exb[(size_t)e * 4 + h] = ev;
    unsafeAtomicAdd(&denom[(size_t)src * 4 + h], ev);
  }
}

__global__ void __launch_bounds__(256) finalize_k(
    const float* __restrict__ exb, const float* __restrict__ denom,
    const int* __restrict__ ei, float* __restrict__ out, int E)
{
  int e = blockIdx.x * 256 + threadIdx.x;
  if (e >= E) return;
  int src = ei[e];
  float4 ev = *(const float4*)(exb + (size_t)e * 4);
  float4 dv = *(const float4*)(denom + (size_t)src * 4);
  out[e] = 0.25f * (ev.x / dv.x + ev.y / dv.y + ev.z / dv.z + ev.w / dv.w);
}

extern "C" void kernel_launch(void* const* d_in, const int* in_sizes, int n_in,
                              void* d_out, int out_size, void* d_ws, size_t ws_size,
                              hipStream_t stream)
{
  const float* x  = (const float*)d_in[0];
  const int*   ei = (const int*)d_in[1];
  const float* W  = (const float*)d_in[2];
  const float* b  = (const float*)d_in[3];

  const int F = in_sizes[2] / in_sizes[3];   // 256
  const int M = in_sizes[0] / F;             // 50000
  const int E = in_sizes[1] / 2;             // 800000

  const int mblocks = (M + GBM - 1) / GBM;
  const int Mpad    = mblocks * GBM;

  // ws: xb | wb | qkb | tl | bias | exb | denom | counts[NBK*CBLK] | sorted[E]
  u16* xb  = (u16*)d_ws;
  u16* wb  = xb + (size_t)Mpad * K_DIM;
  u16* qkb = wb + (size_t)NPAD * K_DIM;
  u16* tl  = qkb + (size_t)M * RQ;
  float* bias  = (float*)(tl + (size_t)M * 8);
  float* exb   = bias + NPAD;
  float* denom = exb + (size_t)E * 4;
  int*   counts = (int*)(denom + (size_t)M * 4);
  uint4* sorted = (uint4*)(counts + NBK * CBLK);

  const int xblocks = (Mpad * (K_DIM / 8) + 255) / 256;
  const int wblocks = (NPAD * (K_DIM / 8) + 255) / 256;
  const int zn      = M * 4;                 // denom only
  const int zblocks = (zn + 255) / 256;
  hipLaunchKernelGGL(prep, dim3(xblocks + wblocks + zblocks), dim3(256), 0, stream,
                     x, W, b, xb, wb, bias, denom, M, Mpad, xblocks, wblocks, zn);

  const int per = (E + CBLK - 1) / CBLK;     // 3125 edges per count/scatter block
  hipLaunchKernelGGL(count_k, dim3(CBLK), dim3(256), 0, stream, ei, counts, E, per);
  hipLaunchKernelGGL(scan_k, dim3(1), dim3(1024), 0, stream, counts);

  dim3 gg(mblocks, NPAD / GBN);
  hipLaunchKernelGGL(gemm_mfma, gg, dim3(256), 0, stream, xb, wb, bias, qkb, tl, M);

  hipLaunchKernelGGL(scatter2_k, dim3(CBLK), dim3(256), 0, stream,
                     ei, counts, sorted, E, per);

  int eblocks = (E + 31) / 32;   // 32 sorted slots per block
  hipLaunchKernelGGL(edge_pass, dim3(eblocks), dim3(256), 0, stream,
                     qkb, tl, sorted, exb, denom, E);

  hipLaunchKernelGGL(finalize_k, dim3((E + 255) / 256), dim3(256), 0, stream,
                     exb, denom, ei, (float*)d_out, E);
}